// Round 10
// baseline (427.784 us; speedup 1.0000x reference)
//
#include <hip/hip_runtime.h>
#include <hip/hip_fp16.h>

#define N_NODES 100000
#define N_EDGES 1600000
#define E_TOT   (N_EDGES + N_NODES)   // 1,700,000 incl. self-loops
#define NEG_SLOPE 0.2f
#define PART_EPB 4096                 // edges per k_part block
#define BSTRIDE 18432                 // slots per bucket region (mean 17408 + 7.8 sigma; fixed input -> deterministic)

// ---------------------------------------------------------------------------
// k_part: partition edges into 128 fixed-stride dst-buckets (dst>>10).
// Only global atomics in the pipeline: one per (block,bucket) range reserve.
// ---------------------------------------------------------------------------
__global__ __launch_bounds__(256)
void k_part(const int* __restrict__ ei, int* __restrict__ bcnt, int2* __restrict__ pairs) {
    const int t = threadIdx.x;
    const int base = blockIdx.x * PART_EPB;
    __shared__ int lcnt[128];
    __shared__ int lbase[128];
    if (t < 128) lcnt[t] = 0;
    __syncthreads();
    int sr[16], dr[16];
#pragma unroll
    for (int u = 0; u < 16; ++u) {
        const int e = base + u * 256 + t;    // coalesced
        if (e < E_TOT) {
            int s, d;
            if (e < N_EDGES) { s = ei[e]; d = ei[N_EDGES + e]; }
            else             { s = d = e - N_EDGES; }
            sr[u] = s; dr[u] = d;
            atomicAdd(&lcnt[d >> 10], 1);    // LDS
        } else dr[u] = -1;
    }
    __syncthreads();
    if (t < 128) {
        const int c = lcnt[t];
        lbase[t] = (c > 0) ? atomicAdd(&bcnt[t], c) : 0;   // global, 1 per bucket
        lcnt[t] = 0;                         // reuse as local cursor
    }
    __syncthreads();
#pragma unroll
    for (int u = 0; u < 16; ++u) {
        if (dr[u] >= 0) {
            const int bk = dr[u] >> 10;
            const int r = atomicAdd(&lcnt[bk], 1);         // LDS
            pairs[(size_t)bk * BSTRIDE + lbase[bk] + r] = make_int2(sr[u], dr[u]);
        }
    }
}

// ---------------------------------------------------------------------------
// k_fill3: one 1024-thread block per bucket. Per-bucket counting sort with
// LDS histogram + LDS cursors — zero global atomics. Also emits ioff/deg
// (buckets are node-ordered so local scan + sbase = global CSR offset).
// ---------------------------------------------------------------------------
__global__ __launch_bounds__(1024)
void k_fill3(const int2* __restrict__ pairs, const int* __restrict__ bcnt,
             int* __restrict__ ioff, int* __restrict__ deg, int* __restrict__ ssrc) {
    const int bucket = blockIdx.x;
    const int t = threadIdx.x;
    const int cnt = bcnt[bucket];
    __shared__ int lhist[1024];
    __shared__ int lcur[1024];
    __shared__ int wsum[16];
    __shared__ int sbase;
    lhist[t] = 0;
    if (t == 0) {                            // edges to all lower buckets
        int b = 0;
        for (int k = 0; k < bucket; ++k) b += bcnt[k];
        sbase = b;
    }
    __syncthreads();
    // Phase A: LDS histogram of local dst
    for (int i = t; i < cnt; i += 1024) {
        const int2 p = pairs[(size_t)bucket * BSTRIDE + i];
        atomicAdd(&lhist[p.y & 1023], 1);
    }
    __syncthreads();
    // Phase B: block-level scan (wave shfl scan + wave-sum scan)
    const int v = lhist[t];
    int inc = v;
    const int lane = t & 63, wid = t >> 6;
#pragma unroll
    for (int o = 1; o < 64; o <<= 1) {
        const int nv = __shfl_up(inc, o, 64);
        if (lane >= o) inc += nv;
    }
    if (lane == 63) wsum[wid] = inc;
    __syncthreads();
    if (t == 0) {
        int acc = 0;
#pragma unroll
        for (int k = 0; k < 16; ++k) { const int tv = wsum[k]; wsum[k] = acc; acc += tv; }
    }
    __syncthreads();
    const int gofs = sbase + (inc - v) + wsum[wid];   // global CSR offset of node d
    const int d = bucket * 1024 + t;
    if (d < N_NODES) { ioff[d] = gofs; deg[d] = v; }  // coalesced, no atomics
    lcur[t] = gofs;
    __syncthreads();
    // Phase C: place edges via LDS cursors
    for (int i = t; i < cnt; i += 1024) {
        const int2 p = pairs[(size_t)bucket * BSTRIDE + i];
        const int pos = atomicAdd(&lcur[p.y & 1023], 1);   // LDS
        ssrc[pos] = p.x;
    }
}

// ---------------------------------------------------------------------------
// Layer 1 GEMM, register-tiled: 256 threads, 32 nodes/block, 4x4 tile/thread.
// fp32 math; xw1 stored fp16.
// ---------------------------------------------------------------------------
__global__ __launch_bounds__(256)
void k_gemm1(const float* __restrict__ x, const float* __restrict__ W1,
             const float* __restrict__ a_src1, const float* __restrict__ a_dst1,
             __half* __restrict__ xw1h, float* __restrict__ al1, float* __restrict__ ar1) {
    const int t = threadIdx.x;
    const int n0 = blockIdx.x * 32;
    __shared__ float sx[32][128];   // 16 KB
    __shared__ float sW[32][128];   // 16 KB (one 32-row k-tile of W1)

    {   // stage x tile: 1024 float4s, coalesced
        const float4* xg = (const float4*)(x + (size_t)n0 * 128);
#pragma unroll
        for (int i = 0; i < 4; ++i) {
            const int f = t + i * 256;
            ((float4*)sx)[f] = xg[f];
        }
    }

    const int tj = t & 31;          // column group: cols 4*tj .. 4*tj+3
    const int tn = (t >> 5) * 4;    // node group:   nodes tn .. tn+3
    float4 acc[4] = {{0,0,0,0},{0,0,0,0},{0,0,0,0},{0,0,0,0}};

    for (int kt = 0; kt < 128; kt += 32) {
        __syncthreads();
        const float4* wg = (const float4*)(W1 + (size_t)kt * 128);
#pragma unroll
        for (int i = 0; i < 4; ++i) {
            const int f = t + i * 256;
            ((float4*)sW)[f] = wg[f];
        }
        __syncthreads();
        for (int k = 0; k < 32; k += 4) {
            float4 xv[4];
#pragma unroll
            for (int i = 0; i < 4; ++i)
                xv[i] = *(const float4*)&sx[tn + i][kt + k];   // broadcast reads
#pragma unroll
            for (int kk = 0; kk < 4; ++kk) {
                const float4 wv = *(const float4*)&sW[k + kk][tj * 4];
#pragma unroll
                for (int i = 0; i < 4; ++i) {
                    const float xs = ((const float*)&xv[i])[kk];
                    acc[i].x = fmaf(xs, wv.x, acc[i].x);
                    acc[i].y = fmaf(xs, wv.y, acc[i].y);
                    acc[i].z = fmaf(xs, wv.z, acc[i].z);
                    acc[i].w = fmaf(xs, wv.w, acc[i].w);
                }
            }
        }
    }

    // write xw1 as fp16 (4 halves = 8B store, aligned)
#pragma unroll
    for (int i = 0; i < 4; ++i) {
        __half hp[4];
        hp[0] = __float2half(acc[i].x);
        hp[1] = __float2half(acc[i].y);
        hp[2] = __float2half(acc[i].z);
        hp[3] = __float2half(acc[i].w);
        *(uint2*)&xw1h[(size_t)(n0 + tn + i) * 128 + tj * 4] = *(uint2*)hp;
    }

    // fused attention dots (fp32): head h = tj>>3
    const float4 asv = ((const float4*)a_src1)[tj];
    const float4 adv = ((const float4*)a_dst1)[tj];
#pragma unroll
    for (int i = 0; i < 4; ++i) {
        float ps = acc[i].x * asv.x + acc[i].y * asv.y + acc[i].z * asv.z + acc[i].w * asv.w;
        float pd = acc[i].x * adv.x + acc[i].y * adv.y + acc[i].z * adv.z + acc[i].w * adv.w;
#pragma unroll
        for (int o = 1; o < 8; o <<= 1) { ps += __shfl_xor(ps, o, 64); pd += __shfl_xor(pd, o, 64); }
        if ((tj & 7) == 0) {
            const int h = tj >> 3;
            al1[(size_t)(n0 + tn + i) * 4 + h] = ps;
            ar1[(size_t)(n0 + tn + i) * 4 + h] = pd;
        }
    }
}

// ---------------------------------------------------------------------------
// Layer 1 pull-aggregation + FUSED layer-2 GEMM (gemm2 kernel eliminated).
// One WAVE per dst node, zero barriers. Lane = g*16+c: 4 edge-groups x 16
// col-lanes; uint4 gathers, inline weights, 8 edges in flight.
// Epilogue: after cross-group reduction every lane holds the full fp32
// h-row fragment (features 8c..8c+7) -> 128x16 GEMM done in-register:
// lane's W2 fragment = rows 8c..8c+7, cols 4g..4g+3 (8 float4 preloads,
// L2-hot), 32 FMAs, shuffle-reduce over the 16 c-lanes. Emits xw2h (fp16)
// and al2/ar2 (fp32) directly. h never leaves registers (more accurate
// than the old fp16 out1h round-trip).
// ---------------------------------------------------------------------------
__global__ __launch_bounds__(256)
void k_aggr1(const int* __restrict__ ssrc, const int* __restrict__ offs,
             const int* __restrict__ deg, const float* __restrict__ al1,
             const float* __restrict__ ar1, const __half* __restrict__ xw1h,
             const float* __restrict__ b1, const float* __restrict__ W2,
             const float* __restrict__ a_src2, const float* __restrict__ a_dst2,
             __half* __restrict__ xw2h, float* __restrict__ al2, float* __restrict__ ar2) {
    const int lane = threadIdx.x & 63;
    const int d = blockIdx.x * 4 + (threadIdx.x >> 6);
    const int g = lane >> 4;                 // edge group 0..3
    const int c = lane & 15;                 // col group: features 8c..8c+7
    const int h = c >> 2;                    // head of this col group
    // W2 fragment: rows 8c..8c+7, cols 4g..4g+3 (16B-aligned float4 rows)
    float4 w2r[8];
#pragma unroll
    for (int i = 0; i < 8; ++i)
        w2r[i] = *(const float4*)&W2[(8 * c + i) * 16 + 4 * g];
    const float4 as2 = *(const float4*)&a_src2[4 * g];
    const float4 ad2 = *(const float4*)&a_dst2[4 * g];
    const float4 b01 = *(const float4*)&b1[c * 8];
    const float4 b23 = *(const float4*)&b1[c * 8 + 4];

    const int beg = offs[d];
    const int n = deg[d];
    const float arh = ar1[(size_t)d * 4 + h];
    float acc[8] = {0.f, 0.f, 0.f, 0.f, 0.f, 0.f, 0.f, 0.f};
    float dnm = 0.f;

    for (int base = 0; base < n; base += 8) {
#pragma unroll
        for (int u = 0; u < 2; ++u) {
            const int e = base + u * 4 + g;
            const bool p = e < n;
            const int s = ssrc[beg + (p ? e : 0)];         // L1-hot (sequential)
            float v = al1[(size_t)s * 4 + h] + arh;        // broadcast gather
            v = v > 0.f ? v : NEG_SLOPE * v;
            const float w = p ? __expf(v) : 0.f;
            const uint4 rv = *(const uint4*)&xw1h[(size_t)s * 128 + c * 8];
            const float2 f0 = __half22float2(*(const __half2*)&rv.x);
            const float2 f1 = __half22float2(*(const __half2*)&rv.y);
            const float2 f2 = __half22float2(*(const __half2*)&rv.z);
            const float2 f3 = __half22float2(*(const __half2*)&rv.w);
            acc[0] = fmaf(w, f0.x, acc[0]); acc[1] = fmaf(w, f0.y, acc[1]);
            acc[2] = fmaf(w, f1.x, acc[2]); acc[3] = fmaf(w, f1.y, acc[3]);
            acc[4] = fmaf(w, f2.x, acc[4]); acc[5] = fmaf(w, f2.y, acc[5]);
            acc[6] = fmaf(w, f3.x, acc[6]); acc[7] = fmaf(w, f3.y, acc[7]);
            dnm += w;
        }
    }
    // reduce across the 4 edge-groups -> all lanes hold full sums
#pragma unroll
    for (int i = 0; i < 8; ++i) {
        acc[i] += __shfl_xor(acc[i], 16, 64);
        acc[i] += __shfl_xor(acc[i], 32, 64);
    }
    dnm += __shfl_xor(dnm, 16, 64);
    dnm += __shfl_xor(dnm, 32, 64);

    // h-row fragment in fp32 (bias + ReLU)
    const float rc = 1.f / dnm;
    const float bb[8] = {b01.x, b01.y, b01.z, b01.w, b23.x, b23.y, b23.z, b23.w};
    float hv[8];
#pragma unroll
    for (int i = 0; i < 8; ++i) {
        const float t = acc[i] * rc + bb[i];
        hv[i] = t > 0.f ? t : 0.f;
    }

    // fused 128x16 GEMM: partial for cols 4g..4g+3 over this lane's 8 rows
    float s0 = 0.f, s1 = 0.f, s2 = 0.f, s3 = 0.f;
#pragma unroll
    for (int i = 0; i < 8; ++i) {
        s0 = fmaf(hv[i], w2r[i].x, s0);
        s1 = fmaf(hv[i], w2r[i].y, s1);
        s2 = fmaf(hv[i], w2r[i].z, s2);
        s3 = fmaf(hv[i], w2r[i].w, s3);
    }
    // reduce over the 16 c-lanes (lane bits 0..3)
#pragma unroll
    for (int o = 1; o < 16; o <<= 1) {
        s0 += __shfl_xor(s0, o, 64);
        s1 += __shfl_xor(s1, o, 64);
        s2 += __shfl_xor(s2, o, 64);
        s3 += __shfl_xor(s3, o, 64);
    }
    if (c == 0) {                            // 4 lanes/node write 8B each, contiguous 32B
        __half hp[4];
        hp[0] = __float2half(s0); hp[1] = __float2half(s1);
        hp[2] = __float2half(s2); hp[3] = __float2half(s3);
        *(uint2*)&xw2h[(size_t)d * 16 + 4 * g] = *(uint2*)hp;
    }
    // layer-2 attention dots
    float ps = s0 * as2.x + s1 * as2.y + s2 * as2.z + s3 * as2.w;
    float pd = s0 * ad2.x + s1 * ad2.y + s2 * ad2.z + s3 * ad2.w;
    ps += __shfl_xor(ps, 16, 64); ps += __shfl_xor(ps, 32, 64);
    pd += __shfl_xor(pd, 16, 64); pd += __shfl_xor(pd, 32, 64);
    if (lane == 0) { al2[d] = ps; ar2[d] = pd; }
}

// ---------------------------------------------------------------------------
// Layer 2 pull-aggregation: one wave per node; 8 edge-groups x 8 half2
// feature-lanes. Cross-group shuffle reduction, fused +b2.
// ---------------------------------------------------------------------------
__global__ __launch_bounds__(256)
void k_aggr2(const int* __restrict__ ssrc, const int* __restrict__ offs,
             const int* __restrict__ deg, const float* __restrict__ al2,
             const float* __restrict__ ar2, const __half* __restrict__ xw2h,
             const float* __restrict__ b2, float* __restrict__ out) {
    const int lane = threadIdx.x & 63;
    const int node = blockIdx.x * 4 + (threadIdx.x >> 6);
    const int j2 = lane & 7;                 // feature pair 2*j2, 2*j2+1
    const int eL = lane >> 3;                // 0..7
    const int beg = offs[node];
    const int n = deg[node];
    const float ard = ar2[node];
    float a0 = 0.f, a1 = 0.f, dnm = 0.f;
    for (int base = 0; base < n; base += 8) {
        const int e = base + eL;
        const bool p = e < n;
        const int s = ssrc[beg + (p ? e : 0)];
        float v = al2[s] + ard;
        v = v > 0.f ? v : NEG_SLOPE * v;
        const float w = p ? __expf(v) : 0.f;
        const float2 f = __half22float2(*(const __half2*)&xw2h[(size_t)s * 16 + j2 * 2]);
        a0 = fmaf(w, f.x, a0);
        a1 = fmaf(w, f.y, a1);
        dnm += w;
    }
#pragma unroll
    for (int o = 8; o < 64; o <<= 1) {
        a0 += __shfl_xor(a0, o, 64);
        a1 += __shfl_xor(a1, o, 64);
        dnm += __shfl_xor(dnm, o, 64);
    }
    if (eL == 0) {
        out[(size_t)node * 16 + j2 * 2]     = a0 / dnm + b2[j2 * 2];
        out[(size_t)node * 16 + j2 * 2 + 1] = a1 / dnm + b2[j2 * 2 + 1];
    }
}

extern "C" void kernel_launch(void* const* d_in, const int* in_sizes, int n_in,
                              void* d_out, int out_size, void* d_ws, size_t ws_size,
                              hipStream_t stream) {
    const float* x      = (const float*)d_in[0];
    const int*   ei     = (const int*)d_in[1];
    const float* W1     = (const float*)d_in[2];
    const float* a_src1 = (const float*)d_in[3];
    const float* a_dst1 = (const float*)d_in[4];
    const float* b1     = (const float*)d_in[5];
    const float* W2     = (const float*)d_in[6];
    const float* a_src2 = (const float*)d_in[7];
    const float* a_dst2 = (const float*)d_in[8];
    const float* b2     = (const float*)d_in[9];
    float* out = (float*)d_out;

    // Workspace (byte-addressed). out1h is gone (gemm2 fused into aggr1), so
    // all regions are disjoint — no aliasing hazards. Total ~59.3 MB.
    char* wsb = (char*)d_ws;
    __half* xw1h = (__half*)wsb;                                  // N*128 half (25.6 MB)
    int2*   pairs = (int2*)(wsb + (size_t)N_NODES * 128 * 2);     // 128*BSTRIDE int2 (18.9 MB)
    char*   p2 = (char*)(pairs + (size_t)128 * BSTRIDE);
    __half* xw2h = (__half*)p2;                                   // N*16 half (3.2 MB)
    float*  al2  = (float*)(p2 + (size_t)N_NODES * 16 * 2);       // N fp32
    float*  ar2  = al2 + N_NODES;                                 // N fp32
    float*  al1  = ar2 + N_NODES;                                 // N*4 fp32
    float*  ar1  = al1 + (size_t)N_NODES * 4;                     // N*4 fp32
    int* ibcnt = (int*)(ar1 + (size_t)N_NODES * 4);               // 128 (zeroed)
    int* ioff  = ibcnt + 128;                                     // N
    int* ideg  = ioff + N_NODES;                                  // N
    int* isrc  = ideg + N_NODES;                                  // E_TOT

    hipMemsetAsync(ibcnt, 0, 128 * sizeof(int), stream);

    // CSR build: bucket partition -> per-bucket counting sort.
    k_part<<<(E_TOT + PART_EPB - 1) / PART_EPB, 256, 0, stream>>>(ei, ibcnt, pairs);
    k_fill3<<<128, 1024, 0, stream>>>(pairs, ibcnt, ioff, ideg, isrc);

    // Layer 1 GEMM + attention logits
    k_gemm1<<<N_NODES / 32, 256, 0, stream>>>(x, W1, a_src1, a_dst1, xw1h, al1, ar1);

    // Layer-1 aggregation with fused layer-2 GEMM (produces xw2h, al2, ar2)
    k_aggr1<<<N_NODES / 4, 256, 0, stream>>>(isrc, ioff, ideg, al1, ar1, xw1h,
                                             b1, W2, a_src2, a_dst2, xw2h, al2, ar2);

    // Layer 2 aggregation -> final output
    k_aggr2<<<N_NODES / 4, 256, 0, stream>>>(isrc, ioff, ideg, al2, ar2, xw2h, b2, out);
}

// Round 11
// 355.427 us; speedup vs baseline: 1.2036x; 1.2036x over previous
//
#include <hip/hip_runtime.h>
#include <hip/hip_fp16.h>

#define N_NODES 100000
#define N_EDGES 1600000
#define E_TOT   (N_EDGES + N_NODES)   // 1,700,000 incl. self-loops
#define NEG_SLOPE 0.2f
#define PART_EPB 4096                 // edges per k_part block
#define BSTRIDE 18432                 // slots per bucket region (mean 17408 + 7.8 sigma; fixed input -> deterministic)

// ---------------------------------------------------------------------------
// k_part: partition edges into 128 fixed-stride dst-buckets (dst>>10).
// Pair entries packed into one int: (src<<10)|(dst&1023) — src<2^17 fits.
// Only global atomics in the pipeline: one per (block,bucket) range reserve.
// ---------------------------------------------------------------------------
__global__ __launch_bounds__(256)
void k_part(const int* __restrict__ ei, int* __restrict__ bcnt, int* __restrict__ pairs) {
    const int t = threadIdx.x;
    const int base = blockIdx.x * PART_EPB;
    __shared__ int lcnt[128];
    __shared__ int lbase[128];
    if (t < 128) lcnt[t] = 0;
    __syncthreads();
    int sr[16], dr[16];
#pragma unroll
    for (int u = 0; u < 16; ++u) {
        const int e = base + u * 256 + t;    // coalesced
        if (e < E_TOT) {
            int s, d;
            if (e < N_EDGES) { s = ei[e]; d = ei[N_EDGES + e]; }
            else             { s = d = e - N_EDGES; }
            sr[u] = s; dr[u] = d;
            atomicAdd(&lcnt[d >> 10], 1);    // LDS
        } else dr[u] = -1;
    }
    __syncthreads();
    if (t < 128) {
        const int c = lcnt[t];
        lbase[t] = (c > 0) ? atomicAdd(&bcnt[t], c) : 0;   // global, 1 per bucket
        lcnt[t] = 0;                         // reuse as local cursor
    }
    __syncthreads();
#pragma unroll
    for (int u = 0; u < 16; ++u) {
        if (dr[u] >= 0) {
            const int bk = dr[u] >> 10;
            const int r = atomicAdd(&lcnt[bk], 1);         // LDS
            pairs[(size_t)bk * BSTRIDE + lbase[bk] + r] = (sr[u] << 10) | (dr[u] & 1023);
        }
    }
}

// ---------------------------------------------------------------------------
// k_fill3: one 1024-thread block per bucket. Per-bucket counting sort with
// LDS histogram + LDS cursors — zero global atomics. Also emits ioff/deg
// (buckets are node-ordered so local scan + sbase = global CSR offset).
// ---------------------------------------------------------------------------
__global__ __launch_bounds__(1024)
void k_fill3(const int* __restrict__ pairs, const int* __restrict__ bcnt,
             int* __restrict__ ioff, int* __restrict__ deg, int* __restrict__ ssrc) {
    const int bucket = blockIdx.x;
    const int t = threadIdx.x;
    const int cnt = bcnt[bucket];
    __shared__ int lhist[1024];
    __shared__ int lcur[1024];
    __shared__ int wsum[16];
    __shared__ int sbase;
    lhist[t] = 0;
    if (t == 0) {                            // edges to all lower buckets
        int b = 0;
        for (int k = 0; k < bucket; ++k) b += bcnt[k];
        sbase = b;
    }
    __syncthreads();
    // Phase A: LDS histogram of local dst
    for (int i = t; i < cnt; i += 1024) {
        const int p = pairs[(size_t)bucket * BSTRIDE + i];
        atomicAdd(&lhist[p & 1023], 1);
    }
    __syncthreads();
    // Phase B: block-level scan (wave shfl scan + wave-sum scan)
    const int v = lhist[t];
    int inc = v;
    const int lane = t & 63, wid = t >> 6;
#pragma unroll
    for (int o = 1; o < 64; o <<= 1) {
        const int nv = __shfl_up(inc, o, 64);
        if (lane >= o) inc += nv;
    }
    if (lane == 63) wsum[wid] = inc;
    __syncthreads();
    if (t == 0) {
        int acc = 0;
#pragma unroll
        for (int k = 0; k < 16; ++k) { const int tv = wsum[k]; wsum[k] = acc; acc += tv; }
    }
    __syncthreads();
    const int gofs = sbase + (inc - v) + wsum[wid];   // global CSR offset of node d
    const int d = bucket * 1024 + t;
    if (d < N_NODES) { ioff[d] = gofs; deg[d] = v; }  // coalesced, no atomics
    lcur[t] = gofs;
    __syncthreads();
    // Phase C: place edges via LDS cursors
    for (int i = t; i < cnt; i += 1024) {
        const int p = pairs[(size_t)bucket * BSTRIDE + i];
        const int pos = atomicAdd(&lcur[p & 1023], 1);     // LDS
        ssrc[pos] = p >> 10;
    }
}

// ---------------------------------------------------------------------------
// Layer 1 GEMM, register-tiled: 256 threads, 32 nodes/block, 4x4 tile/thread.
// fp32 math; xw1 stored fp16.
// ---------------------------------------------------------------------------
__global__ __launch_bounds__(256)
void k_gemm1(const float* __restrict__ x, const float* __restrict__ W1,
             const float* __restrict__ a_src1, const float* __restrict__ a_dst1,
             __half* __restrict__ xw1h, float* __restrict__ al1, float* __restrict__ ar1) {
    const int t = threadIdx.x;
    const int n0 = blockIdx.x * 32;
    __shared__ float sx[32][128];   // 16 KB
    __shared__ float sW[32][128];   // 16 KB (one 32-row k-tile of W1)

    {   // stage x tile: 1024 float4s, coalesced
        const float4* xg = (const float4*)(x + (size_t)n0 * 128);
#pragma unroll
        for (int i = 0; i < 4; ++i) {
            const int f = t + i * 256;
            ((float4*)sx)[f] = xg[f];
        }
    }

    const int tj = t & 31;          // column group: cols 4*tj .. 4*tj+3
    const int tn = (t >> 5) * 4;    // node group:   nodes tn .. tn+3
    float4 acc[4] = {{0,0,0,0},{0,0,0,0},{0,0,0,0},{0,0,0,0}};

    for (int kt = 0; kt < 128; kt += 32) {
        __syncthreads();
        const float4* wg = (const float4*)(W1 + (size_t)kt * 128);
#pragma unroll
        for (int i = 0; i < 4; ++i) {
            const int f = t + i * 256;
            ((float4*)sW)[f] = wg[f];
        }
        __syncthreads();
        for (int k = 0; k < 32; k += 4) {
            float4 xv[4];
#pragma unroll
            for (int i = 0; i < 4; ++i)
                xv[i] = *(const float4*)&sx[tn + i][kt + k];   // broadcast reads
#pragma unroll
            for (int kk = 0; kk < 4; ++kk) {
                const float4 wv = *(const float4*)&sW[k + kk][tj * 4];
#pragma unroll
                for (int i = 0; i < 4; ++i) {
                    const float xs = ((const float*)&xv[i])[kk];
                    acc[i].x = fmaf(xs, wv.x, acc[i].x);
                    acc[i].y = fmaf(xs, wv.y, acc[i].y);
                    acc[i].z = fmaf(xs, wv.z, acc[i].z);
                    acc[i].w = fmaf(xs, wv.w, acc[i].w);
                }
            }
        }
    }

    // write xw1 as fp16 (4 halves = 8B store, aligned)
#pragma unroll
    for (int i = 0; i < 4; ++i) {
        __half hp[4];
        hp[0] = __float2half(acc[i].x);
        hp[1] = __float2half(acc[i].y);
        hp[2] = __float2half(acc[i].z);
        hp[3] = __float2half(acc[i].w);
        *(uint2*)&xw1h[(size_t)(n0 + tn + i) * 128 + tj * 4] = *(uint2*)hp;
    }

    // fused attention dots (fp32): head h = tj>>3
    const float4 asv = ((const float4*)a_src1)[tj];
    const float4 adv = ((const float4*)a_dst1)[tj];
#pragma unroll
    for (int i = 0; i < 4; ++i) {
        float ps = acc[i].x * asv.x + acc[i].y * asv.y + acc[i].z * asv.z + acc[i].w * asv.w;
        float pd = acc[i].x * adv.x + acc[i].y * adv.y + acc[i].z * adv.z + acc[i].w * adv.w;
#pragma unroll
        for (int o = 1; o < 8; o <<= 1) { ps += __shfl_xor(ps, o, 64); pd += __shfl_xor(pd, o, 64); }
        if ((tj & 7) == 0) {
            const int h = tj >> 3;
            al1[(size_t)(n0 + tn + i) * 4 + h] = ps;
            ar1[(size_t)(n0 + tn + i) * 4 + h] = pd;
        }
    }
}

// ---------------------------------------------------------------------------
// Layer 1 pull-aggregation (R9 version — VGPR 20, 73% occupancy, 91us):
// one WAVE per dst node, zero barriers. Lane = g*16+c: 4 edge-groups x 16
// col-lanes; uint4 gathers, inline weights, 8 edges in flight. NOTE (R10
// post-mortem): do NOT preload epilogue state across this loop — +24 VGPR
// halved occupancy and doubled duration on this latency-bound gather.
// ---------------------------------------------------------------------------
__global__ __launch_bounds__(256)
void k_aggr1(const int* __restrict__ ssrc, const int* __restrict__ offs,
             const int* __restrict__ deg, const float* __restrict__ al1,
             const float* __restrict__ ar1, const __half* __restrict__ xw1h,
             const float* __restrict__ b1, __half* __restrict__ out1h) {
    const int lane = threadIdx.x & 63;
    const int d = blockIdx.x * 4 + (threadIdx.x >> 6);
    const int g = lane >> 4;                 // edge group 0..3
    const int c = lane & 15;                 // col group: features 8c..8c+7
    const int h = c >> 2;                    // head of this col group
    const int beg = offs[d];
    const int n = deg[d];
    const float arh = ar1[(size_t)d * 4 + h];
    float acc[8] = {0.f, 0.f, 0.f, 0.f, 0.f, 0.f, 0.f, 0.f};
    float dnm = 0.f;

    for (int base = 0; base < n; base += 8) {
#pragma unroll
        for (int u = 0; u < 2; ++u) {
            const int e = base + u * 4 + g;
            const bool p = e < n;
            const int s = ssrc[beg + (p ? e : 0)];         // L1-hot (sequential)
            float v = al1[(size_t)s * 4 + h] + arh;        // broadcast gather
            v = v > 0.f ? v : NEG_SLOPE * v;
            const float w = p ? __expf(v) : 0.f;
            const uint4 rv = *(const uint4*)&xw1h[(size_t)s * 128 + c * 8];
            const float2 f0 = __half22float2(*(const __half2*)&rv.x);
            const float2 f1 = __half22float2(*(const __half2*)&rv.y);
            const float2 f2 = __half22float2(*(const __half2*)&rv.z);
            const float2 f3 = __half22float2(*(const __half2*)&rv.w);
            acc[0] = fmaf(w, f0.x, acc[0]); acc[1] = fmaf(w, f0.y, acc[1]);
            acc[2] = fmaf(w, f1.x, acc[2]); acc[3] = fmaf(w, f1.y, acc[3]);
            acc[4] = fmaf(w, f2.x, acc[4]); acc[5] = fmaf(w, f2.y, acc[5]);
            acc[6] = fmaf(w, f3.x, acc[6]); acc[7] = fmaf(w, f3.y, acc[7]);
            dnm += w;
        }
    }
#pragma unroll
    for (int i = 0; i < 8; ++i) {
        acc[i] += __shfl_xor(acc[i], 16, 64);
        acc[i] += __shfl_xor(acc[i], 32, 64);
    }
    dnm += __shfl_xor(dnm, 16, 64);
    dnm += __shfl_xor(dnm, 32, 64);
    if (g == 0) {
        const float rc = 1.f / dnm;
        const float4 b01 = *(const float4*)&b1[c * 8];
        const float4 b23 = *(const float4*)&b1[c * 8 + 4];
        const float bb[8] = {b01.x, b01.y, b01.z, b01.w, b23.x, b23.y, b23.z, b23.w};
        __half ho[8];
#pragma unroll
        for (int i = 0; i < 8; ++i) {
            const float hv = acc[i] * rc + bb[i];
            ho[i] = __float2half(hv > 0.f ? hv : 0.f);     // bias + ReLU
        }
        *(uint4*)&out1h[(size_t)d * 128 + c * 8] = *(uint4*)ho;
    }
}

// ---------------------------------------------------------------------------
// Layer 2 GEMM: 16 nodes/block, 256 threads. Reads fp16 out1, fp32 math,
// xw2 stored fp16, al2/ar2 fp32.
// ---------------------------------------------------------------------------
__global__ __launch_bounds__(256)
void k_gemm2(const __half* __restrict__ out1h, const float* __restrict__ W2,
             const float* __restrict__ a_src2, const float* __restrict__ a_dst2,
             __half* __restrict__ xw2h, float* __restrict__ al2, float* __restrict__ ar2) {
    const int t = threadIdx.x;
    const int node0 = blockIdx.x * 16;
    __shared__ float sW[128 * 16];
    __shared__ float sh[16][129];            // +1 pad: kills 4-way bank conflict
    for (int i = t; i < 2048; i += 256) sW[i] = W2[i];
    for (int i = t; i < 2048; i += 256) {
        const int nn = i >> 7, kk = i & 127;
        sh[nn][kk] = __half2float(out1h[(size_t)(node0 + nn) * 128 + kk]);
    }
    __syncthreads();
    const int nn = t >> 4;                   // 0..15
    const int j = t & 15;
    float acc = 0.f;
#pragma unroll 8
    for (int k = 0; k < 128; ++k)
        acc = fmaf(sh[nn][k], sW[k * 16 + j], acc);
    xw2h[(size_t)(node0 + nn) * 16 + j] = __float2half(acc);

    float ps = acc * a_src2[j];
    float pd = acc * a_dst2[j];
#pragma unroll
    for (int o = 8; o; o >>= 1) { ps += __shfl_xor(ps, o, 64); pd += __shfl_xor(pd, o, 64); }
    if (j == 0) { al2[node0 + nn] = ps; ar2[node0 + nn] = pd; }
}

// ---------------------------------------------------------------------------
// Layer 2 pull-aggregation: one wave per node; 8 edge-groups x 8 half2
// feature-lanes, x2 unroll -> 16 edges in flight. Shuffle reduction, +b2.
// ---------------------------------------------------------------------------
__global__ __launch_bounds__(256)
void k_aggr2(const int* __restrict__ ssrc, const int* __restrict__ offs,
             const int* __restrict__ deg, const float* __restrict__ al2,
             const float* __restrict__ ar2, const __half* __restrict__ xw2h,
             const float* __restrict__ b2, float* __restrict__ out) {
    const int lane = threadIdx.x & 63;
    const int node = blockIdx.x * 4 + (threadIdx.x >> 6);
    const int j2 = lane & 7;                 // feature pair 2*j2, 2*j2+1
    const int eL = lane >> 3;                // 0..7
    const int beg = offs[node];
    const int n = deg[node];
    const float ard = ar2[node];
    float a0 = 0.f, a1 = 0.f, dnm = 0.f;
    for (int base = 0; base < n; base += 16) {
#pragma unroll
        for (int u = 0; u < 2; ++u) {
            const int e = base + u * 8 + eL;
            const bool p = e < n;
            const int s = ssrc[beg + (p ? e : 0)];
            float v = al2[s] + ard;
            v = v > 0.f ? v : NEG_SLOPE * v;
            const float w = p ? __expf(v) : 0.f;
            const float2 f = __half22float2(*(const __half2*)&xw2h[(size_t)s * 16 + j2 * 2]);
            a0 = fmaf(w, f.x, a0);
            a1 = fmaf(w, f.y, a1);
            dnm += w;
        }
    }
#pragma unroll
    for (int o = 8; o < 64; o <<= 1) {
        a0 += __shfl_xor(a0, o, 64);
        a1 += __shfl_xor(a1, o, 64);
        dnm += __shfl_xor(dnm, o, 64);
    }
    if (eL == 0) {
        out[(size_t)node * 16 + j2 * 2]     = a0 / dnm + b2[j2 * 2];
        out[(size_t)node * 16 + j2 * 2 + 1] = a1 / dnm + b2[j2 * 2 + 1];
    }
}

extern "C" void kernel_launch(void* const* d_in, const int* in_sizes, int n_in,
                              void* d_out, int out_size, void* d_ws, size_t ws_size,
                              hipStream_t stream) {
    const float* x      = (const float*)d_in[0];
    const int*   ei     = (const int*)d_in[1];
    const float* W1     = (const float*)d_in[2];
    const float* a_src1 = (const float*)d_in[3];
    const float* a_dst1 = (const float*)d_in[4];
    const float* b1     = (const float*)d_in[5];
    const float* W2     = (const float*)d_in[6];
    const float* a_src2 = (const float*)d_in[7];
    const float* a_dst2 = (const float*)d_in[8];
    const float* b2     = (const float*)d_in[9];
    float* out = (float*)d_out;

    // Workspace (byte-addressed). Aliases:
    //  - pairs (9.4MB packed) sits in out1h's region (25.6MB): consumed by
    //    k_fill3 before k_aggr1 writes out1h.
    //  - xw2h/al2/ar2 sit in xw1h's region: written by k_gemm2 after k_aggr1
    //    is done with xw1h.
    char* wsb = (char*)d_ws;
    __half* xw1h = (__half*)wsb;                                  // N*128 half (25.6 MB)
    __half* xw2h = (__half*)wsb;                                  // N*16 half (alias)
    float*  al2  = (float*)(wsb + (size_t)N_NODES * 16 * 2);      // N fp32 (alias)
    float*  ar2  = al2 + N_NODES;                                 // N fp32 (alias)
    __half* out1h = (__half*)(wsb + (size_t)N_NODES * 128 * 2);   // N*128 half (25.6 MB)
    int*    pairs = (int*)out1h;                                  // 128*BSTRIDE int (alias, 9.4 MB)
    float*  al1  = (float*)(wsb + (size_t)N_NODES * 128 * 4);     // N*4 fp32
    float*  ar1  = al1 + (size_t)N_NODES * 4;                     // N*4
    int* ibcnt = (int*)(ar1 + (size_t)N_NODES * 4);               // 128 (zeroed)
    int* ioff  = ibcnt + 128;                                     // N
    int* ideg  = ioff + N_NODES;                                  // N
    int* isrc  = ideg + N_NODES;                                  // E_TOT

    hipMemsetAsync(ibcnt, 0, 128 * sizeof(int), stream);

    // CSR build: bucket partition -> per-bucket counting sort.
    k_part<<<(E_TOT + PART_EPB - 1) / PART_EPB, 256, 0, stream>>>(ei, ibcnt, pairs);
    k_fill3<<<128, 1024, 0, stream>>>(pairs, ibcnt, ioff, ideg, isrc);

    // Layer 1
    k_gemm1<<<N_NODES / 32, 256, 0, stream>>>(x, W1, a_src1, a_dst1, xw1h, al1, ar1);
    k_aggr1<<<N_NODES / 4, 256, 0, stream>>>(isrc, ioff, ideg, al1, ar1, xw1h, b1, out1h);

    // Layer 2
    k_gemm2<<<N_NODES / 16, 256, 0, stream>>>(out1h, W2, a_src2, a_dst2, xw2h, al2, ar2);
    k_aggr2<<<N_NODES / 4, 256, 0, stream>>>(isrc, ioff, ideg, al2, ar2, xw2h, b2, out);
}

// Round 12
// 336.023 us; speedup vs baseline: 1.2731x; 1.0577x over previous
//
#include <hip/hip_runtime.h>
#include <hip/hip_fp16.h>

#define N_NODES 100000
#define N_EDGES 1600000
#define E_TOT   (N_EDGES + N_NODES)   // 1,700,000 incl. self-loops
#define NEG_SLOPE 0.2f
#define PART_EPB 4096                 // edges per partition block
#define BSTRIDE 18432                 // slots per bucket region (mean 17408 + 7.8 sigma)
#define NGEMM (N_NODES / 32)          // 3125 gemm blocks
#define NPART ((E_TOT + PART_EPB - 1) / PART_EPB)   // 416 partition blocks

using f16x8 = __attribute__((ext_vector_type(8))) _Float16;
using f32x4 = __attribute__((ext_vector_type(4))) float;
union H8 { f16x8 v; _Float16 h[8]; };

// ---------------------------------------------------------------------------
// Merged kernel: blocks < NGEMM do the layer-1 GEMM via MFMA (fp16 in, fp32
// acc — we already round xw1 to fp16 on store, so input rounding adds error
// of the same magnitude). Blocks >= NGEMM do the edge bucket-partition
// (zero data dependency between the roles -> one dispatch, overlapped).
//
// GEMM role: 32 nodes x 128 cols/block, 4 waves; wave w owns head w's 32
// cols for all 32 nodes (4 16x16 tiles, 16 MFMA). A-frags stream from x;
// B-frags scalar-load from L2-hot W1. Layouts (HW-verified, cdna docs):
//   A[m=lane&15][k=quad*8+i], B[k=quad*8+i][n=lane&15],
//   C/D: col=lane&15, row=quad*4+reg.
// No LDS, no barriers in the GEMM path.
// ---------------------------------------------------------------------------
__global__ __launch_bounds__(256)
void k_gemm1_part(const float* __restrict__ x, const float* __restrict__ W1,
                  const float* __restrict__ a_src1, const float* __restrict__ a_dst1,
                  const int* __restrict__ ei, int* __restrict__ bcnt, int* __restrict__ pairs,
                  __half* __restrict__ xw1h, float* __restrict__ al1, float* __restrict__ ar1) {
    __shared__ int lcnt[128];
    __shared__ int lbase[128];
    const int t = threadIdx.x;

    if (blockIdx.x >= NGEMM) {
        // ===== edge-partition role (was k_part) =====
        const int base = ((int)blockIdx.x - NGEMM) * PART_EPB;
        if (t < 128) lcnt[t] = 0;
        __syncthreads();
        int sr[16], dr[16];
#pragma unroll
        for (int u = 0; u < 16; ++u) {
            const int e = base + u * 256 + t;    // coalesced
            if (e < E_TOT) {
                int s, d;
                if (e < N_EDGES) { s = ei[e]; d = ei[N_EDGES + e]; }
                else             { s = d = e - N_EDGES; }
                sr[u] = s; dr[u] = d;
                atomicAdd(&lcnt[d >> 10], 1);    // LDS
            } else dr[u] = -1;
        }
        __syncthreads();
        if (t < 128) {
            const int c = lcnt[t];
            lbase[t] = (c > 0) ? atomicAdd(&bcnt[t], c) : 0;   // global, 1/bucket
            lcnt[t] = 0;
        }
        __syncthreads();
#pragma unroll
        for (int u = 0; u < 16; ++u) {
            if (dr[u] >= 0) {
                const int bk = dr[u] >> 10;
                const int r = atomicAdd(&lcnt[bk], 1);         // LDS
                pairs[(size_t)bk * BSTRIDE + lbase[bk] + r] = (sr[u] << 10) | (dr[u] & 1023);
            }
        }
        return;
    }

    // ===== MFMA GEMM role =====
    const int lane = t & 63;
    const int w = t >> 6;                    // wave id == head id
    const int q = lane >> 4;                 // quad
    const int n15 = lane & 15;
    const int n0 = (int)blockIdx.x * 32;
    const int j0 = (2 * w) * 16 + n15;       // col in tile 0 of this head
    const int j1 = (2 * w + 1) * 16 + n15;   // col in tile 1

    f32x4 acc00 = {0.f, 0.f, 0.f, 0.f};
    f32x4 acc01 = acc00, acc10 = acc00, acc11 = acc00;

    for (int kt = 0; kt < 4; ++kt) {
        const int k0 = kt * 32 + q * 8;
        H8 A0, A1, B0, B1;
        {
            const float4* p = (const float4*)&x[(size_t)(n0 + n15) * 128 + k0];
            const float4 xa = p[0], xb = p[1];
            A0.h[0] = (_Float16)xa.x; A0.h[1] = (_Float16)xa.y;
            A0.h[2] = (_Float16)xa.z; A0.h[3] = (_Float16)xa.w;
            A0.h[4] = (_Float16)xb.x; A0.h[5] = (_Float16)xb.y;
            A0.h[6] = (_Float16)xb.z; A0.h[7] = (_Float16)xb.w;
        }
        {
            const float4* p = (const float4*)&x[(size_t)(n0 + 16 + n15) * 128 + k0];
            const float4 xa = p[0], xb = p[1];
            A1.h[0] = (_Float16)xa.x; A1.h[1] = (_Float16)xa.y;
            A1.h[2] = (_Float16)xa.z; A1.h[3] = (_Float16)xa.w;
            A1.h[4] = (_Float16)xb.x; A1.h[5] = (_Float16)xb.y;
            A1.h[6] = (_Float16)xb.z; A1.h[7] = (_Float16)xb.w;
        }
#pragma unroll
        for (int i = 0; i < 8; ++i) {
            B0.h[i] = (_Float16)W1[(size_t)(k0 + i) * 128 + j0];   // 16 lanes -> 64B runs, L2-hot
            B1.h[i] = (_Float16)W1[(size_t)(k0 + i) * 128 + j1];
        }
        acc00 = __builtin_amdgcn_mfma_f32_16x16x32_f16(A0.v, B0.v, acc00, 0, 0, 0);
        acc01 = __builtin_amdgcn_mfma_f32_16x16x32_f16(A0.v, B1.v, acc01, 0, 0, 0);
        acc10 = __builtin_amdgcn_mfma_f32_16x16x32_f16(A1.v, B0.v, acc10, 0, 0, 0);
        acc11 = __builtin_amdgcn_mfma_f32_16x16x32_f16(A1.v, B1.v, acc11, 0, 0, 0);
    }

    // Epilogue: D col = n15-based j, row m = q*4 + r. Fused attention dots.
    const float as0 = a_src1[j0], as1 = a_src1[j1];
    const float ad0 = a_dst1[j0], ad1 = a_dst1[j1];
#pragma unroll
    for (int ng = 0; ng < 2; ++ng) {
        const f32x4 accA = ng ? acc10 : acc00;
        const f32x4 accB = ng ? acc11 : acc01;
#pragma unroll
        for (int r = 0; r < 4; ++r) {
            const int node = n0 + ng * 16 + q * 4 + r;
            xw1h[(size_t)node * 128 + j0] = __float2half(accA[r]);   // 32B runs/quad
            xw1h[(size_t)node * 128 + j1] = __float2half(accB[r]);
            float ps = accA[r] * as0 + accB[r] * as1;
            float pd = accA[r] * ad0 + accB[r] * ad1;
#pragma unroll
            for (int o = 1; o < 16; o <<= 1) {   // reduce over the 16 j-lanes (quad preserved)
                ps += __shfl_xor(ps, o, 64);
                pd += __shfl_xor(pd, o, 64);
            }
            if (n15 == 0) {
                al1[(size_t)node * 4 + w] = ps;
                ar1[(size_t)node * 4 + w] = pd;
            }
        }
    }
}

// ---------------------------------------------------------------------------
// k_fill3: one 1024-thread block per bucket. Per-bucket counting sort with
// LDS histogram + LDS cursors — zero global atomics. Also emits ioff/deg.
// ---------------------------------------------------------------------------
__global__ __launch_bounds__(1024)
void k_fill3(const int* __restrict__ pairs, const int* __restrict__ bcnt,
             int* __restrict__ ioff, int* __restrict__ deg, int* __restrict__ ssrc) {
    const int bucket = blockIdx.x;
    const int t = threadIdx.x;
    const int cnt = bcnt[bucket];
    __shared__ int lhist[1024];
    __shared__ int lcur[1024];
    __shared__ int wsum[16];
    __shared__ int sbase;
    lhist[t] = 0;
    if (t == 0) {                            // edges to all lower buckets
        int b = 0;
        for (int k = 0; k < bucket; ++k) b += bcnt[k];
        sbase = b;
    }
    __syncthreads();
    for (int i = t; i < cnt; i += 1024) {
        const int p = pairs[(size_t)bucket * BSTRIDE + i];
        atomicAdd(&lhist[p & 1023], 1);
    }
    __syncthreads();
    const int v = lhist[t];
    int inc = v;
    const int lane = t & 63, wid = t >> 6;
#pragma unroll
    for (int o = 1; o < 64; o <<= 1) {
        const int nv = __shfl_up(inc, o, 64);
        if (lane >= o) inc += nv;
    }
    if (lane == 63) wsum[wid] = inc;
    __syncthreads();
    if (t == 0) {
        int acc = 0;
#pragma unroll
        for (int k = 0; k < 16; ++k) { const int tv = wsum[k]; wsum[k] = acc; acc += tv; }
    }
    __syncthreads();
    const int gofs = sbase + (inc - v) + wsum[wid];   // global CSR offset of node d
    const int d = bucket * 1024 + t;
    if (d < N_NODES) { ioff[d] = gofs; deg[d] = v; }
    lcur[t] = gofs;
    __syncthreads();
    for (int i = t; i < cnt; i += 1024) {
        const int p = pairs[(size_t)bucket * BSTRIDE + i];
        const int pos = atomicAdd(&lcur[p & 1023], 1);     // LDS
        ssrc[pos] = p >> 10;
    }
}

// ---------------------------------------------------------------------------
// Layer 1 pull-aggregation (VGPR 20 — do NOT preload epilogue state, R10).
// One wave per dst node, zero barriers; uint4 gathers, 8 edges in flight.
// ---------------------------------------------------------------------------
__global__ __launch_bounds__(256)
void k_aggr1(const int* __restrict__ ssrc, const int* __restrict__ offs,
             const int* __restrict__ deg, const float* __restrict__ al1,
             const float* __restrict__ ar1, const __half* __restrict__ xw1h,
             const float* __restrict__ b1, __half* __restrict__ out1h) {
    const int lane = threadIdx.x & 63;
    const int d = blockIdx.x * 4 + (threadIdx.x >> 6);
    const int g = lane >> 4;                 // edge group 0..3
    const int c = lane & 15;                 // col group: features 8c..8c+7
    const int h = c >> 2;                    // head of this col group
    const int beg = offs[d];
    const int n = deg[d];
    const float arh = ar1[(size_t)d * 4 + h];
    float acc[8] = {0.f, 0.f, 0.f, 0.f, 0.f, 0.f, 0.f, 0.f};
    float dnm = 0.f;

    for (int base = 0; base < n; base += 8) {
#pragma unroll
        for (int u = 0; u < 2; ++u) {
            const int e = base + u * 4 + g;
            const bool p = e < n;
            const int s = ssrc[beg + (p ? e : 0)];         // L1-hot (sequential)
            float v = al1[(size_t)s * 4 + h] + arh;        // broadcast gather
            v = v > 0.f ? v : NEG_SLOPE * v;
            const float w = p ? __expf(v) : 0.f;
            const uint4 rv = *(const uint4*)&xw1h[(size_t)s * 128 + c * 8];
            const float2 f0 = __half22float2(*(const __half2*)&rv.x);
            const float2 f1 = __half22float2(*(const __half2*)&rv.y);
            const float2 f2 = __half22float2(*(const __half2*)&rv.z);
            const float2 f3 = __half22float2(*(const __half2*)&rv.w);
            acc[0] = fmaf(w, f0.x, acc[0]); acc[1] = fmaf(w, f0.y, acc[1]);
            acc[2] = fmaf(w, f1.x, acc[2]); acc[3] = fmaf(w, f1.y, acc[3]);
            acc[4] = fmaf(w, f2.x, acc[4]); acc[5] = fmaf(w, f2.y, acc[5]);
            acc[6] = fmaf(w, f3.x, acc[6]); acc[7] = fmaf(w, f3.y, acc[7]);
            dnm += w;
        }
    }
#pragma unroll
    for (int i = 0; i < 8; ++i) {
        acc[i] += __shfl_xor(acc[i], 16, 64);
        acc[i] += __shfl_xor(acc[i], 32, 64);
    }
    dnm += __shfl_xor(dnm, 16, 64);
    dnm += __shfl_xor(dnm, 32, 64);
    if (g == 0) {
        const float rc = 1.f / dnm;
        const float4 b01 = *(const float4*)&b1[c * 8];
        const float4 b23 = *(const float4*)&b1[c * 8 + 4];
        const float bb[8] = {b01.x, b01.y, b01.z, b01.w, b23.x, b23.y, b23.z, b23.w};
        __half ho[8];
#pragma unroll
        for (int i = 0; i < 8; ++i) {
            const float hv = acc[i] * rc + bb[i];
            ho[i] = __float2half(hv > 0.f ? hv : 0.f);     // bias + ReLU
        }
        *(uint4*)&out1h[(size_t)d * 128 + c * 8] = *(uint4*)ho;
    }
}

// ---------------------------------------------------------------------------
// Layer 2 GEMM: 16 nodes/block, 256 threads.
// ---------------------------------------------------------------------------
__global__ __launch_bounds__(256)
void k_gemm2(const __half* __restrict__ out1h, const float* __restrict__ W2,
             const float* __restrict__ a_src2, const float* __restrict__ a_dst2,
             __half* __restrict__ xw2h, float* __restrict__ al2, float* __restrict__ ar2) {
    const int t = threadIdx.x;
    const int node0 = blockIdx.x * 16;
    __shared__ float sW[128 * 16];
    __shared__ float sh[16][129];            // +1 pad: kills 4-way bank conflict
    for (int i = t; i < 2048; i += 256) sW[i] = W2[i];
    for (int i = t; i < 2048; i += 256) {
        const int nn = i >> 7, kk = i & 127;
        sh[nn][kk] = __half2float(out1h[(size_t)(node0 + nn) * 128 + kk]);
    }
    __syncthreads();
    const int nn = t >> 4;                   // 0..15
    const int j = t & 15;
    float acc = 0.f;
#pragma unroll 8
    for (int k = 0; k < 128; ++k)
        acc = fmaf(sh[nn][k], sW[k * 16 + j], acc);
    xw2h[(size_t)(node0 + nn) * 16 + j] = __float2half(acc);

    float ps = acc * a_src2[j];
    float pd = acc * a_dst2[j];
#pragma unroll
    for (int o = 8; o; o >>= 1) { ps += __shfl_xor(ps, o, 64); pd += __shfl_xor(pd, o, 64); }
    if (j == 0) { al2[node0 + nn] = ps; ar2[node0 + nn] = pd; }
}

// ---------------------------------------------------------------------------
// Layer 2 pull-aggregation: one wave per node; 16 edges in flight.
// ---------------------------------------------------------------------------
__global__ __launch_bounds__(256)
void k_aggr2(const int* __restrict__ ssrc, const int* __restrict__ offs,
             const int* __restrict__ deg, const float* __restrict__ al2,
             const float* __restrict__ ar2, const __half* __restrict__ xw2h,
             const float* __restrict__ b2, float* __restrict__ out) {
    const int lane = threadIdx.x & 63;
    const int node = blockIdx.x * 4 + (threadIdx.x >> 6);
    const int j2 = lane & 7;                 // feature pair 2*j2, 2*j2+1
    const int eL = lane >> 3;                // 0..7
    const int beg = offs[node];
    const int n = deg[node];
    const float ard = ar2[node];
    float a0 = 0.f, a1 = 0.f, dnm = 0.f;
    for (int base = 0; base < n; base += 16) {
#pragma unroll
        for (int u = 0; u < 2; ++u) {
            const int e = base + u * 8 + eL;
            const bool p = e < n;
            const int s = ssrc[beg + (p ? e : 0)];
            float v = al2[s] + ard;
            v = v > 0.f ? v : NEG_SLOPE * v;
            const float w = p ? __expf(v) : 0.f;
            const float2 f = __half22float2(*(const __half2*)&xw2h[(size_t)s * 16 + j2 * 2]);
            a0 = fmaf(w, f.x, a0);
            a1 = fmaf(w, f.y, a1);
            dnm += w;
        }
    }
#pragma unroll
    for (int o = 8; o < 64; o <<= 1) {
        a0 += __shfl_xor(a0, o, 64);
        a1 += __shfl_xor(a1, o, 64);
        dnm += __shfl_xor(dnm, o, 64);
    }
    if (eL == 0) {
        out[(size_t)node * 16 + j2 * 2]     = a0 / dnm + b2[j2 * 2];
        out[(size_t)node * 16 + j2 * 2 + 1] = a1 / dnm + b2[j2 * 2 + 1];
    }
}

extern "C" void kernel_launch(void* const* d_in, const int* in_sizes, int n_in,
                              void* d_out, int out_size, void* d_ws, size_t ws_size,
                              hipStream_t stream) {
    const float* x      = (const float*)d_in[0];
    const int*   ei     = (const int*)d_in[1];
    const float* W1     = (const float*)d_in[2];
    const float* a_src1 = (const float*)d_in[3];
    const float* a_dst1 = (const float*)d_in[4];
    const float* b1     = (const float*)d_in[5];
    const float* W2     = (const float*)d_in[6];
    const float* a_src2 = (const float*)d_in[7];
    const float* a_dst2 = (const float*)d_in[8];
    const float* b2     = (const float*)d_in[9];
    float* out = (float*)d_out;

    // Workspace (byte-addressed). Aliases:
    //  - pairs (9.4MB packed) sits in out1h's region: consumed by k_fill3
    //    before k_aggr1 writes out1h.
    //  - xw2h/al2/ar2 sit in xw1h's region: written by k_gemm2 after k_aggr1
    //    is done with xw1h.
    char* wsb = (char*)d_ws;
    __half* xw1h = (__half*)wsb;                                  // N*128 half (25.6 MB)
    __half* xw2h = (__half*)wsb;                                  // N*16 half (alias)
    float*  al2  = (float*)(wsb + (size_t)N_NODES * 16 * 2);      // N fp32 (alias)
    float*  ar2  = al2 + N_NODES;                                 // N fp32 (alias)
    __half* out1h = (__half*)(wsb + (size_t)N_NODES * 128 * 2);   // N*128 half (25.6 MB)
    int*    pairs = (int*)out1h;                                  // 128*BSTRIDE int (alias, 9.4 MB)
    float*  al1  = (float*)(wsb + (size_t)N_NODES * 128 * 4);     // N*4 fp32
    float*  ar1  = al1 + (size_t)N_NODES * 4;                     // N*4
    int* ibcnt = (int*)(ar1 + (size_t)N_NODES * 4);               // 128 (zeroed)
    int* ioff  = ibcnt + 128;                                     // N
    int* ideg  = ioff + N_NODES;                                  // N
    int* isrc  = ideg + N_NODES;                                  // E_TOT

    hipMemsetAsync(ibcnt, 0, 128 * sizeof(int), stream);

    // Merged: MFMA layer-1 GEMM + edge bucket partition (independent roles).
    k_gemm1_part<<<NGEMM + NPART, 256, 0, stream>>>(x, W1, a_src1, a_dst1,
                                                    ei, ibcnt, pairs, xw1h, al1, ar1);
    // Per-bucket counting sort -> CSR (ioff/ideg/isrc).
    k_fill3<<<128, 1024, 0, stream>>>(pairs, ibcnt, ioff, ideg, isrc);

    // Layer 1 aggregation
    k_aggr1<<<N_NODES / 4, 256, 0, stream>>>(isrc, ioff, ideg, al1, ar1, xw1h, b1, out1h);

    // Layer 2
    k_gemm2<<<N_NODES / 16, 256, 0, stream>>>(out1h, W2, a_src2, a_dst2, xw2h, al2, ar2);
    k_aggr2<<<N_NODES / 4, 256, 0, stream>>>(isrc, ioff, ideg, al2, ar2, xw2h, b2, out);
}